// Round 1
// baseline (377.920 us; speedup 1.0000x reference)
//
#include <hip/hip_runtime.h>

typedef short s16x8 __attribute__((ext_vector_type(8)));
typedef float f32x4 __attribute__((ext_vector_type(4)));

#define N_SAMPLES 65536
#define DIM 768
#define HID 384
#define NEXP 8
#define NCLS 8

// workspace layout (bytes)
#define WS_CNT    0
#define WS_BUCKET 1024
#define WS_W1T    (WS_BUCKET + NEXP * N_SAMPLES * 4)   // 2,098,176
#define WS_W2T    (WS_W1T + NEXP * HID * DIM * 2)      // 6,816,768
// total ~6.87 MB

__device__ __forceinline__ unsigned short f2bf(float f) {
  union { float f; unsigned u; } v; v.f = f;
  unsigned r = v.u + 0x7fffu + ((v.u >> 16) & 1u);   // RNE, finite inputs
  return (unsigned short)(r >> 16);
}

// W1[e][k=768][j=384] f32  ->  W1T[e][j=384][k=768] bf16
__global__ void k_transpose_w1(const float* __restrict__ W1,
                               unsigned short* __restrict__ W1T) {
  __shared__ float tile[32][33];
  const int e = blockIdx.z, k0 = blockIdx.x * 32, j0 = blockIdx.y * 32;
  const int tx = threadIdx.x, ty = threadIdx.y;
  const float* src = W1 + (size_t)e * DIM * HID;
#pragma unroll
  for (int i = 0; i < 32; i += 8)
    tile[ty + i][tx] = src[(size_t)(k0 + ty + i) * HID + j0 + tx];
  __syncthreads();
  unsigned short* dst = W1T + (size_t)e * HID * DIM;
#pragma unroll
  for (int i = 0; i < 32; i += 8)
    dst[(size_t)(j0 + ty + i) * DIM + k0 + tx] = f2bf(tile[tx][ty + i]);
}

// W2[e][j=384][c=8] f32 -> W2T[e][c=8][j=384] bf16 ; zero bucket counters
__global__ void k_w2_cnt(const float* __restrict__ W2,
                         unsigned short* __restrict__ W2T,
                         int* __restrict__ cnt) {
  const int e = blockIdx.x, j = threadIdx.x;
  if (e == 0 && j < NEXP) cnt[j] = 0;
#pragma unroll
  for (int c = 0; c < NCLS; ++c)
    W2T[((size_t)e * NCLS + c) * HID + j] = f2bf(W2[((size_t)e * HID + j) * NCLS + c]);
}

// bucket rows by expert (block-local LDS histogram -> 1 global atomic per expert
// per block), and initialize out[i][:] = b2[qt[i]][:]
__global__ void k_scatter_init(const int* __restrict__ qt, const float* __restrict__ b2,
                               int* __restrict__ cnt, int* __restrict__ bucket,
                               float* __restrict__ out) {
  __shared__ int lcnt[NEXP], lbase[NEXP];
  const int t = threadIdx.x;
  const int i = blockIdx.x * 256 + t;
  if (t < NEXP) lcnt[t] = 0;
  __syncthreads();
  const int e = qt[i];
  const int rank = atomicAdd(&lcnt[e], 1);
  __syncthreads();
  if (t < NEXP) lbase[t] = atomicAdd(&cnt[t], lcnt[t]);
  __syncthreads();
  bucket[(size_t)e * N_SAMPLES + lbase[e] + rank] = i;
  const float4* b2v = (const float4*)(b2 + e * NCLS);
  float4* ov = (float4*)(out + (size_t)i * NCLS);
  ov[0] = b2v[0];
  ov[1] = b2v[1];
}

#define GLL16(g, l)                                                        \
  __builtin_amdgcn_global_load_lds(                                        \
      (__attribute__((address_space(1))) void*)(void*)(g),                 \
      (__attribute__((address_space(3))) void*)(l), 16, 0, 0)

// grouped gather-GEMM: per block = (expert e, 128 gathered rows, 128 of 384 H)
// h = relu(x_bf16 @ W1T_bf16 + b1); out[rows] += h @ W2  (fp32 atomic partials)
__global__ __launch_bounds__(256, 2) void k_moe_gemm(
    const float* __restrict__ x, const unsigned short* __restrict__ W1T,
    const float* __restrict__ b1, const unsigned short* __restrict__ W2T,
    const int* __restrict__ cnt, const int* __restrict__ bucket,
    float* __restrict__ out) {
  // Hs (128 x 136 bf16, 34816 B) aliases As(8KB)+Bs(8KB): epilogue runs after
  // the final K-loop barrier, so the overlap is safe and saves ~16KB LDS.
  __shared__ __align__(16) short smem[17408];
  __shared__ __align__(16) short W2s[16 * 128];
  __shared__ float b1s[128];
  __shared__ int idxs[128];
  short* As = smem;          // [128 m][32 k] bf16
  short* Bs = smem + 4096;   // [128 j][32 k] bf16
  short* Hs = smem;          // [128 m][136 j] bf16

  const int e = blockIdx.z;
  const int n_e = cnt[e];
  const int j0 = blockIdx.x * 128;           // h-tile base (0,128,256)
  const int t = threadIdx.x;
  const int lane = t & 63;
  const int wave = t >> 6;
  const int lrow = lane & 15;
  const int quad = lane >> 4;
  const int lk = quad * 8;
  const int mbase = (wave & 1) * 64;
  const int nbase = (wave >> 1) * 64;

  // per-block persistent preloads (independent of row tile)
  {
    const int c = t >> 4, jj = (t & 15) * 8;
    s16x8 wv = {0, 0, 0, 0, 0, 0, 0, 0};
    if (c < NCLS) wv = *(const s16x8*)&W2T[((size_t)e * NCLS + c) * HID + j0 + jj];
    *(s16x8*)&W2s[c * 128 + jj] = wv;       // [c(16, zero-padded)][j(128)]
  }
  if (t < 128) b1s[t] = b1[e * HID + j0 + t];

  for (int rt = blockIdx.y; rt * 128 < n_e; rt += gridDim.y) {
    const int row0 = rt * 128;
    __syncthreads();   // prev-iter epilogue LDS reads done / first-iter preloads done
    if (t < 128) {
      const int slot = row0 + t;
      idxs[t] = bucket[(size_t)e * N_SAMPLES + ((slot < n_e) ? slot : row0)];
    }
    __syncthreads();

    // A staging map: thread t -> row t>>1, k-half (t&1)*16 (pairs cover 128B/row)
    const float* xrow = x + (size_t)idxs[t >> 1] * DIM + (t & 1) * 16;
    // B staging map: flat 16B unit f = rep*256+t -> j=f>>2, k=(f&3)*8
    const unsigned short* g0 = W1T + ((size_t)(e * HID + j0 + (t >> 2)) * DIM + (t & 3) * 8);
    const unsigned short* g1 = W1T + ((size_t)(e * HID + j0 + 64 + (t >> 2)) * DIM + (t & 3) * 8);

    f32x4 acc[4][4];
#pragma unroll
    for (int mi = 0; mi < 4; ++mi)
#pragma unroll
      for (int ni = 0; ni < 4; ++ni) acc[mi][ni] = (f32x4){0.f, 0.f, 0.f, 0.f};

    float4 v0 = ((const float4*)xrow)[0];
    float4 v1 = ((const float4*)xrow)[1];
    float4 v2 = ((const float4*)xrow)[2];
    float4 v3 = ((const float4*)xrow)[3];

    for (int ks = 0; ks < 24; ++ks) {
      // stage A (fp32 -> bf16 in VGPR -> two ds_write_b128)
      s16x8 p0 = {(short)f2bf(v0.x), (short)f2bf(v0.y), (short)f2bf(v0.z), (short)f2bf(v0.w),
                  (short)f2bf(v1.x), (short)f2bf(v1.y), (short)f2bf(v1.z), (short)f2bf(v1.w)};
      s16x8 p1 = {(short)f2bf(v2.x), (short)f2bf(v2.y), (short)f2bf(v2.z), (short)f2bf(v2.w),
                  (short)f2bf(v3.x), (short)f2bf(v3.y), (short)f2bf(v3.z), (short)f2bf(v3.w)};
      *(s16x8*)&As[t * 16] = p0;
      *(s16x8*)&As[t * 16 + 8] = p1;
      // stage B: async global->LDS, 16B/lane
      GLL16(g0 + ks * 32, &Bs[t * 8]);
      GLL16(g1 + ks * 32, &Bs[2048 + t * 8]);
      __syncthreads();
      if (ks < 23) {  // prefetch next A chunk; latency hidden under MFMAs
        const float4* nx = (const float4*)(xrow + (ks + 1) * 32);
        v0 = nx[0]; v1 = nx[1]; v2 = nx[2]; v3 = nx[3];
      }
      s16x8 bfr[4];
#pragma unroll
      for (int ni = 0; ni < 4; ++ni)
        bfr[ni] = *(const s16x8*)&Bs[(nbase + ni * 16 + lrow) * 32 + lk];
#pragma unroll
      for (int mi = 0; mi < 4; ++mi) {
        s16x8 afr = *(const s16x8*)&As[(mbase + mi * 16 + lrow) * 32 + lk];
#pragma unroll
        for (int ni = 0; ni < 4; ++ni)
          acc[mi][ni] = __builtin_amdgcn_mfma_f32_16x16x32_bf16(afr, bfr[ni], acc[mi][ni], 0, 0, 0);
      }
      __syncthreads();
    }

    // epilogue 1: bias + relu, C-layout (col=lane&15,row=quad*4+r) -> Hs bf16
#pragma unroll
    for (int ni = 0; ni < 4; ++ni) {
      const int jl = nbase + ni * 16 + lrow;
      const float bias = b1s[jl];
#pragma unroll
      for (int mi = 0; mi < 4; ++mi) {
        const int mrow = mbase + mi * 16 + quad * 4;
#pragma unroll
        for (int r = 0; r < 4; ++r) {
          float v = acc[mi][ni][r] + bias;
          v = v > 0.f ? v : 0.f;
          Hs[(mrow + r) * 136 + jl] = (short)f2bf(v);
        }
      }
    }
    __syncthreads();

    // epilogue 2: layer-2 MFMA (M=128 over 8 m-tiles, N=16 (8 valid), K=128)
#pragma unroll
    for (int p = 0; p < 2; ++p) {
      const int mt = wave * 2 + p;
      f32x4 acc2 = (f32x4){0.f, 0.f, 0.f, 0.f};
#pragma unroll
      for (int kk = 0; kk < 4; ++kk) {
        s16x8 af = *(const s16x8*)&Hs[(mt * 16 + lrow) * 136 + kk * 32 + lk];
        s16x8 bf = *(const s16x8*)&W2s[lrow * 128 + kk * 32 + lk];
        acc2 = __builtin_amdgcn_mfma_f32_16x16x32_bf16(af, bf, acc2, 0, 0, 0);
      }
      if (lrow < NCLS) {
#pragma unroll
        for (int r = 0; r < 4; ++r) {
          const int m = mt * 16 + quad * 4 + r;
          if (row0 + m < n_e)
            atomicAdd(out + (size_t)idxs[m] * NCLS + lrow, acc2[r]);
        }
      }
    }
  }
}

extern "C" void kernel_launch(void* const* d_in, const int* in_sizes, int n_in,
                              void* d_out, int out_size, void* d_ws, size_t ws_size,
                              hipStream_t stream) {
  const float* x  = (const float*)d_in[0];
  const float* W1 = (const float*)d_in[1];
  const float* b1 = (const float*)d_in[2];
  const float* W2 = (const float*)d_in[3];
  const float* b2 = (const float*)d_in[4];
  const int* qt   = (const int*)d_in[5];
  float* out = (float*)d_out;
  char* ws = (char*)d_ws;

  int* cnt = (int*)(ws + WS_CNT);
  int* bucket = (int*)(ws + WS_BUCKET);
  unsigned short* W1T = (unsigned short*)(ws + WS_W1T);
  unsigned short* W2T = (unsigned short*)(ws + WS_W2T);

  k_transpose_w1<<<dim3(24, 12, 8), dim3(32, 8), 0, stream>>>(W1, W1T);
  k_w2_cnt<<<dim3(8), dim3(384), 0, stream>>>(W2, W2T, cnt);
  k_scatter_init<<<dim3(256), dim3(256), 0, stream>>>(qt, b2, cnt, bucket, out);
  k_moe_gemm<<<dim3(3, 96, 8), dim3(256), 0, stream>>>(x, W1T, b1, W2T, cnt, bucket, out);
}